// Round 1
// baseline (1212.205 us; speedup 1.0000x reference)
//
#include <hip/hip_runtime.h>

// Problem constants (fixed shapes from setup_inputs)
constexpr int BS = 16;      // batch (both vis and txt)
constexpr int S  = 4096;    // 16*16*16 spatial
constexpr int E  = 128;     // embedding
constexpr int T  = 64;      // text tokens
constexpr int CHUNK  = 16;  // s-rows per iteration
constexpr int NCHUNK = S / CHUNK;  // 256
constexpr int VROW = E + 4; // padded LDS row (float4-aligned, breaks pow2 banks)

__device__ __forceinline__ float wave_allreduce_sum(float x) {
#pragma unroll
    for (int m = 1; m < 64; m <<= 1) x += __shfl_xor(x, m);
    return x;
}

// One block per (i = txt sample, b = vis sample). 512 threads = 8 waves.
// Thread identity for compute phases: t = tid & 63 (token), c = tid >> 6 (16-float e-chunk).
__global__ __launch_bounds__(512, 1)
void clip_main_kernel(const float* __restrict__ vis,
                      const float* __restrict__ txt,
                      float* __restrict__ d_out,
                      float* __restrict__ ws)
{
    __shared__ float vlds[CHUNK * VROW];   // normalized vis rows, 8.4 KB
    __shared__ float part[8 * CHUNK * T];  // logit partials [c][ss][t], 32 KB (reused for cos partials)
    __shared__ float esm[CHUNK * (T + 1)]; // e = exp(4*s1), padded 65, 4.2 KB
    __shared__ float dpart[8 * T];         // per-wave partials, 2 KB
    __shared__ float dlds[T];              // final denom per token

    const int tid = threadIdx.x;
    const int t = tid & 63;
    const int c = tid >> 6;
    const int i = blockIdx.x & 15;   // txt sample
    const int b = blockIdx.x >> 4;   // vis sample
    const bool diag = (i == b);

    // ---- load + L2-normalize text fragment tn[i][t][16c .. 16c+16) into registers ----
    float tnreg[16];
    {
        const float* tp = txt + ((long)i * T + t) * E + (c << 4);
        float ssq = 0.f;
#pragma unroll
        for (int j = 0; j < 16; ++j) { tnreg[j] = tp[j]; ssq = fmaf(tnreg[j], tnreg[j], ssq); }
        dpart[(c << 6) + t] = ssq;
        __syncthreads();
        float tot = 0.f;
#pragma unroll
        for (int w = 0; w < 8; ++w) tot += dpart[(w << 6) + t];
        const float inv = 1.0f / fmaxf(sqrtf(tot), 1e-12f);
#pragma unroll
        for (int j = 0; j < 16; ++j) tnreg[j] *= inv;
        __syncthreads();
    }

    float wcr[16];  // unnormalized weighted-context accumulator, e-chunk c of token t
#pragma unroll
    for (int j = 0; j < 16; ++j) wcr[j] = 0.f;
    float dpriv = 0.f;  // private partial of denom[t] over this wave's s subset

    const float* visb = vis + (long)b * S * E;
    float* attb = d_out + 1 + (long)b * (long)T * S;  // att_maps[b][t][s]

    for (int ch = 0; ch < NCHUNK; ++ch) {
        const int s0 = ch * CHUNK;

        // ---- stage 16 vis rows, L2-normalize on the fly (32 threads / row) ----
        {
            float4 v = ((const float4*)(visb + (long)s0 * E))[tid];
            float ssq = v.x * v.x + v.y * v.y + v.z * v.z + v.w * v.w;
#pragma unroll
            for (int m = 1; m < 32; m <<= 1) ssq += __shfl_xor(ssq, m);
            const float inv = 1.0f / fmaxf(sqrtf(ssq), 1e-12f);
            v.x *= inv; v.y *= inv; v.z *= inv; v.w *= inv;
            ((float4*)(vlds + (tid >> 5) * VROW))[tid & 31] = v;
        }
        __syncthreads();

        // ---- logit partials: p[ss] = <v[ss][16c..], tnreg> (broadcast LDS reads) ----
        float p[CHUNK];
#pragma unroll
        for (int ss = 0; ss < CHUNK; ++ss) {
            const float4* vr = (const float4*)(vlds + ss * VROW + (c << 4));
            const float4 x0 = vr[0], x1 = vr[1], x2 = vr[2], x3 = vr[3];
            float acc;
            acc  = x0.x * tnreg[0]  + x0.y * tnreg[1]  + x0.z * tnreg[2]  + x0.w * tnreg[3];
            acc += x1.x * tnreg[4]  + x1.y * tnreg[5]  + x1.z * tnreg[6]  + x1.w * tnreg[7];
            acc += x2.x * tnreg[8]  + x2.y * tnreg[9]  + x2.z * tnreg[10] + x2.w * tnreg[11];
            acc += x3.x * tnreg[12] + x3.y * tnreg[13] + x3.z * tnreg[14] + x3.w * tnreg[15];
            p[ss] = acc;
        }
#pragma unroll
        for (int ss = 0; ss < CHUNK; ++ss)
            part[((c << 4) + ss) * 64 + t] = p[ss];
        __syncthreads();

        // ---- reduce partials, softmax over t (wave-wide), e = exp(4*s1) ----
#pragma unroll
        for (int m = 0; m < 2; ++m) {
            const int ss = c + (m << 3);  // each wave owns ss = c and c+8
            float lg = 0.f;
#pragma unroll
            for (int w = 0; w < 8; ++w) lg += part[((w << 4) + ss) * 64 + t];
            // |lg| <= ~1 (unit dots): no max-subtraction needed
            const float ex = __expf(lg);
            const float sum = wave_allreduce_sum(ex);
            const float ev = __expf(4.0f * (ex / sum));  // in [1, e^4]: no overflow ever
            esm[ss * 65 + t] = ev;
            dpriv += ev;
        }
        __syncthreads();

        // ---- wc accumulate: wcr += e[ss][t] * v[ss][16c..] ----
#pragma unroll 4
        for (int ss = 0; ss < CHUNK; ++ss) {
            const float e = esm[ss * 65 + t];
            const float4* vr = (const float4*)(vlds + ss * VROW + (c << 4));
            const float4 x0 = vr[0], x1 = vr[1], x2 = vr[2], x3 = vr[3];
            wcr[0]  = fmaf(e, x0.x, wcr[0]);  wcr[1]  = fmaf(e, x0.y, wcr[1]);
            wcr[2]  = fmaf(e, x0.z, wcr[2]);  wcr[3]  = fmaf(e, x0.w, wcr[3]);
            wcr[4]  = fmaf(e, x1.x, wcr[4]);  wcr[5]  = fmaf(e, x1.y, wcr[5]);
            wcr[6]  = fmaf(e, x1.z, wcr[6]);  wcr[7]  = fmaf(e, x1.w, wcr[7]);
            wcr[8]  = fmaf(e, x2.x, wcr[8]);  wcr[9]  = fmaf(e, x2.y, wcr[9]);
            wcr[10] = fmaf(e, x2.z, wcr[10]); wcr[11] = fmaf(e, x2.w, wcr[11]);
            wcr[12] = fmaf(e, x3.x, wcr[12]); wcr[13] = fmaf(e, x3.y, wcr[13]);
            wcr[14] = fmaf(e, x3.z, wcr[14]); wcr[15] = fmaf(e, x3.w, wcr[15]);
        }

        // ---- diagonal blocks: emit UNNORMALIZED e to att_maps region (scaled later) ----
        if (diag) {
#pragma unroll
            for (int k = 0; k < 2; ++k) {
                const int idx = (k << 9) + tid;
                const int tt = idx >> 4, sl = idx & 15;
                attb[(long)tt * S + s0 + sl] = esm[sl * 65 + tt];
            }
        }
        __syncthreads();
    }

    // ---- denom[t] = sum over waves of dpriv ----
    dpart[(c << 6) + t] = dpriv;
    __syncthreads();
    if (tid < 64) {
        float s = 0.f;
#pragma unroll
        for (int w = 0; w < 8; ++w) s += dpart[(w << 6) + t];
        dlds[t] = s;
        if (diag) ws[256 + (b << 6) + t] = s;  // for att normalization kernel
    }
    __syncthreads();

    // ---- cosine similarity + row log-sum-exp ----
    float nump = 0.f, w2p = 0.f, w1p = 0.f;
#pragma unroll
    for (int j = 0; j < 16; ++j) {
        nump = fmaf(wcr[j], tnreg[j], nump);
        w2p  = fmaf(wcr[j], wcr[j], w2p);
        w1p  = fmaf(tnreg[j], tnreg[j], w1p);
    }
    float* cpA = part;
    float* cpB = part + 512;
    float* cpC = part + 1024;
    cpA[(c << 6) + t] = nump;
    cpB[(c << 6) + t] = w2p;
    cpC[(c << 6) + t] = w1p;
    __syncthreads();
    if (tid < 64) {
        float num = 0.f, w2s = 0.f, w1s = 0.f;
#pragma unroll
        for (int w = 0; w < 8; ++w) {
            num += cpA[(w << 6) + t];
            w2s += cpB[(w << 6) + t];
            w1s += cpC[(w << 6) + t];
        }
        const float dn = dlds[t];
        num /= dn;                        // true wc . tn
        const float w2 = sqrtf(w2s) / dn; // ||wc||
        const float w1 = sqrtf(w1s);      // ||tn|| (~1)
        const float cosv = num / fmaxf(w1 * w2, 1e-8f);
        float r = __expf(5.0f * cosv);
        r = wave_allreduce_sum(r);        // sum over tokens t
        if (t == 0) ws[(b << 4) + i] = 10.0f * logf(r);  // sims[b][i]
    }
}

// att_maps[b][t][:] *= 1/denom[b][t]. Region starts at d_out+1 (4B misaligned) -> b32 ops.
__global__ __launch_bounds__(256, 4)
void att_norm_kernel(float* __restrict__ d_out, const float* __restrict__ ws)
{
    const int bt = blockIdx.x;                 // b*64 + t
    const float inv = 1.0f / ws[256 + bt];
    float* p = d_out + 1 + (long)bt * 4096;
#pragma unroll
    for (int k = 0; k < 16; ++k)
        p[k * 256 + threadIdx.x] *= inv;
}

// Final 16x16 symmetric cross-entropy. One block.
__global__ __launch_bounds__(256, 1)
void loss_kernel(const float* __restrict__ ws, float* __restrict__ d_out)
{
    __shared__ float sm[16][17];
    __shared__ float red[16];
    const int tid = threadIdx.x;
    const int bb = tid >> 4, ii = tid & 15;
    const float x = ws[bb * 16 + ii];  // sims[bb][ii]
    sm[bb][ii] = x;

    // logp0 diag: row softmax over ii (16-lane shuffle groups)
    float m = x;
#pragma unroll
    for (int msk = 1; msk < 16; msk <<= 1) m = fmaxf(m, __shfl_xor(m, msk));
    float s = __expf(x - m);
#pragma unroll
    for (int msk = 1; msk < 16; msk <<= 1) s += __shfl_xor(s, msk);
    const float lsm0 = x - m - logf(s);

    __syncthreads();
    const float y = sm[ii][bb];  // sims[ii][bb]: group-reduce over ii == over rows of column bb
    float m1 = y;
#pragma unroll
    for (int msk = 1; msk < 16; msk <<= 1) m1 = fmaxf(m1, __shfl_xor(m1, msk));
    float s1 = __expf(y - m1);
#pragma unroll
    for (int msk = 1; msk < 16; msk <<= 1) s1 += __shfl_xor(s1, msk);
    const float lsm1 = y - m1 - logf(s1);

    if (bb == ii) red[bb] = lsm0 + lsm1;
    __syncthreads();
    if (tid == 0) {
        float tot = 0.f;
#pragma unroll
        for (int k = 0; k < 16; ++k) tot += red[k];
        d_out[0] = -tot / 32.0f;  // (loss0 + loss1)/2, each a mean over 16 diag terms
    }
}

extern "C" void kernel_launch(void* const* d_in, const int* in_sizes, int n_in,
                              void* d_out, int out_size, void* d_ws, size_t ws_size,
                              hipStream_t stream)
{
    const float* vis = (const float*)d_in[0];  // [16,16,16,16,128]
    const float* txt = (const float*)d_in[1];  // [16,64,128]
    float* out = (float*)d_out;                // [0]=loss, [1..] = att_maps [16,64,4096]
    float* ws  = (float*)d_ws;                 // [0..255] sims, [256..1279] diag denoms

    hipLaunchKernelGGL(clip_main_kernel, dim3(BS * BS), dim3(512), 0, stream,
                       vis, txt, out, ws);
    hipLaunchKernelGGL(att_norm_kernel, dim3(BS * T), dim3(256), 0, stream,
                       out, ws);
    hipLaunchKernelGGL(loss_kernel, dim3(1), dim3(256), 0, stream, ws, out);
}

// Round 2
// 309.462 us; speedup vs baseline: 3.9171x; 3.9171x over previous
//
#include <hip/hip_runtime.h>

constexpr int BS = 16;     // batch (vis and txt)
constexpr int S  = 4096;   // spatial 16*16*16
constexpr int E  = 128;    // embedding
constexpr int T  = 64;     // text tokens
constexpr int CH = 64;     // s-rows per chunk
constexpr int NCH = S / CH;

typedef __attribute__((ext_vector_type(8))) short bf16x8;
typedef __attribute__((ext_vector_type(4))) float f32x4;

__device__ __forceinline__ unsigned short f2bf(float x) {
    unsigned u = __float_as_uint(x);
    u += 0x7FFFu + ((u >> 16) & 1u);          // RTNE
    return (unsigned short)(u >> 16);
}
__device__ __forceinline__ float bf2f(unsigned short v) {
    return __uint_as_float(((unsigned)v) << 16);
}

// One block per (i,b). 256 threads = 4 waves. GEMM1: D=attn0^T (M=t via tn-in-regs,
// N=s-tile per wave). GEMM2: D=wc^T[e][t] (A=Vt LDS, B=et LDS).
__global__ __launch_bounds__(256, 1)
void clip_main_kernel(const float* __restrict__ vis,
                      const float* __restrict__ txt,
                      float* __restrict__ d_out,
                      float* __restrict__ ws)
{
    __shared__ unsigned short Vt[128 * 72];   // Vt[e][s] bf16, stride 72 (18.4 KB)
    __shared__ unsigned short ET[64 * 72];    // et[t][s] bf16, stride 72 (9.2 KB)
    __shared__ float invn[64];                // per-row inv L2 norms (current chunk)
    __shared__ float red [256];               // cross-wave reduce scratch
    __shared__ float red2[256];

    const int tid = threadIdx.x;
    const int w   = tid >> 6;     // wave 0..3
    const int l   = tid & 63;
    const int cl  = l & 15;       // MFMA col lane
    const int q   = l >> 4;       // quad
    const int b   = blockIdx.x & 15;   // vis sample (b%8 -> XCD: 2 vis tiles per XCD L2)
    const int i   = blockIdx.x >> 4;   // txt sample
    const bool diag = (i == b);

    // ---- setup: tn A-frags in registers (A[m=t: lane cl][k=e: q*8+j]) ----
    float  tinv[4];
    bf16x8 tA[4][4];   // [m-tile][k-step]
#pragma unroll
    for (int mt = 0; mt < 4; ++mt) {
        const float* tp = txt + ((long)i * T + mt * 16 + cl) * E + (q << 3);
        float x[4][8];
        float ssq = 0.f;
#pragma unroll
        for (int kk = 0; kk < 4; ++kk) {
            const float4 a0 = *(const float4*)(tp + (kk << 5));
            const float4 a1 = *(const float4*)(tp + (kk << 5) + 4);
            x[kk][0]=a0.x; x[kk][1]=a0.y; x[kk][2]=a0.z; x[kk][3]=a0.w;
            x[kk][4]=a1.x; x[kk][5]=a1.y; x[kk][6]=a1.z; x[kk][7]=a1.w;
#pragma unroll
            for (int j = 0; j < 8; ++j) ssq = fmaf(x[kk][j], x[kk][j], ssq);
        }
        ssq += __shfl_xor(ssq, 16);
        ssq += __shfl_xor(ssq, 32);
        const float inv = 1.0f / fmaxf(sqrtf(ssq), 1e-12f);
        tinv[mt] = inv;
#pragma unroll
        for (int kk = 0; kk < 4; ++kk) {
            bf16x8 f;
#pragma unroll
            for (int j = 0; j < 8; ++j) f[j] = (short)f2bf(x[kk][j] * inv);
            tA[mt][kk] = f;
        }
    }

    f32x4 acc2[2][4];   // wc^T[e=w*32+mt2*16+q*4+r][t=n1*16+cl]
#pragma unroll
    for (int a = 0; a < 2; ++a)
#pragma unroll
        for (int n = 0; n < 4; ++n) acc2[a][n] = (f32x4){0.f, 0.f, 0.f, 0.f};
    float dnacc[16];
#pragma unroll
    for (int k = 0; k < 16; ++k) dnacc[k] = 0.f;

    const float* visb = vis + (long)b * S * E;
    float* attb = d_out + 1 + (long)b * (long)T * S;

    for (int ch = 0; ch < NCH; ++ch) {
        const int s0 = ch * CH;

        // ---- stage Vt[e][s] + invn (packed s-pairs; conflict-free b32 writes) ----
        {
            const int pp = tid >> 3, ee = tid & 7;
            const float* rA = visb + (long)(s0 + (pp << 1)) * E + (ee << 1);
            float2 va[8], vb[8];
            float sa = 0.f, sb = 0.f;
#pragma unroll
            for (int k = 0; k < 8; ++k) {
                va[k] = *(const float2*)(rA + (k << 4));
                vb[k] = *(const float2*)(rA + E + (k << 4));
                sa = fmaf(va[k].x, va[k].x, fmaf(va[k].y, va[k].y, sa));
                sb = fmaf(vb[k].x, vb[k].x, fmaf(vb[k].y, vb[k].y, sb));
            }
            sa += __shfl_xor(sa, 1); sa += __shfl_xor(sa, 2); sa += __shfl_xor(sa, 4);
            sb += __shfl_xor(sb, 1); sb += __shfl_xor(sb, 2); sb += __shfl_xor(sb, 4);
            const float ia = 1.0f / fmaxf(sqrtf(sa), 1e-12f);
            const float ib = 1.0f / fmaxf(sqrtf(sb), 1e-12f);
            if (ee == 0) { invn[pp << 1] = ia; invn[(pp << 1) + 1] = ib; }
#pragma unroll
            for (int k = 0; k < 8; ++k) {
                const int e0 = (ee << 1) + (k << 4);
                unsigned lo = (unsigned)f2bf(va[k].x * ia) | ((unsigned)f2bf(vb[k].x * ib) << 16);
                unsigned hi = (unsigned)f2bf(va[k].y * ia) | ((unsigned)f2bf(vb[k].y * ib) << 16);
                *(unsigned*)&Vt[e0 * 72 + (pp << 1)]       = lo;
                *(unsigned*)&Vt[(e0 + 1) * 72 + (pp << 1)] = hi;
            }
        }
        __syncthreads();

        // ---- GEMM1: B-frags direct from global (normalized), MFMA vs tn regs ----
        f32x4 acc1[4];
#pragma unroll
        for (int mt = 0; mt < 4; ++mt) acc1[mt] = (f32x4){0.f, 0.f, 0.f, 0.f};
        {
            const float* rowp = visb + (long)(s0 + (w << 4) + cl) * E + (q << 3);
            const float invr = invn[(w << 4) + cl];
            bf16x8 Bf[4];
#pragma unroll
            for (int kk = 0; kk < 4; ++kk) {
                const float4 a0 = *(const float4*)(rowp + (kk << 5));
                const float4 a1 = *(const float4*)(rowp + (kk << 5) + 4);
                bf16x8 f;
                f[0]=(short)f2bf(a0.x*invr); f[1]=(short)f2bf(a0.y*invr);
                f[2]=(short)f2bf(a0.z*invr); f[3]=(short)f2bf(a0.w*invr);
                f[4]=(short)f2bf(a1.x*invr); f[5]=(short)f2bf(a1.y*invr);
                f[6]=(short)f2bf(a1.z*invr); f[7]=(short)f2bf(a1.w*invr);
                Bf[kk] = f;
            }
#pragma unroll
            for (int kk = 0; kk < 4; ++kk)
#pragma unroll
                for (int mt = 0; mt < 4; ++mt)
                    acc1[mt] = __builtin_amdgcn_mfma_f32_16x16x32_bf16(tA[mt][kk], Bf[kk], acc1[mt], 0, 0, 0);
        }

        // ---- softmax over t at own s=cl column; e = exp(4*s1); scatter to ET ----
        {
            float ex[4][4];
            float ssum = 0.f;
#pragma unroll
            for (int mt = 0; mt < 4; ++mt)
#pragma unroll
                for (int r = 0; r < 4; ++r) {
                    const float v = __expf(acc1[mt][r]);   // |logit| <= ~1
                    ex[mt][r] = v; ssum += v;
                }
            ssum += __shfl_xor(ssum, 16);
            ssum += __shfl_xor(ssum, 32);
            const float csc = 4.0f / ssum;
            const int sloc = (w << 4) + cl;
#pragma unroll
            for (int mt = 0; mt < 4; ++mt)
#pragma unroll
                for (int r = 0; r < 4; ++r) {
                    const float e = __expf(ex[mt][r] * csc);   // in [1, e^4]
                    ET[(mt * 16 + (q << 2) + r) * 72 + sloc] = f2bf(e);
                    dnacc[mt * 4 + r] += e;
                }
        }
        __syncthreads();

        // ---- GEMM2: wc^T[e][t] += Vt-frags x ET-frags ----
        {
            bf16x8 aV[2][2], bE[4][2];
#pragma unroll
            for (int mt2 = 0; mt2 < 2; ++mt2)
#pragma unroll
                for (int kk2 = 0; kk2 < 2; ++kk2)
                    aV[mt2][kk2] = *(const bf16x8*)&Vt[((w << 5) + (mt2 << 4) + cl) * 72 + (kk2 << 5) + (q << 3)];
#pragma unroll
            for (int n1 = 0; n1 < 4; ++n1)
#pragma unroll
                for (int kk2 = 0; kk2 < 2; ++kk2)
                    bE[n1][kk2] = *(const bf16x8*)&ET[((n1 << 4) + cl) * 72 + (kk2 << 5) + (q << 3)];
#pragma unroll
            for (int kk2 = 0; kk2 < 2; ++kk2)
#pragma unroll
                for (int mt2 = 0; mt2 < 2; ++mt2)
#pragma unroll
                    for (int n1 = 0; n1 < 4; ++n1)
                        acc2[mt2][n1] = __builtin_amdgcn_mfma_f32_16x16x32_bf16(aV[mt2][kk2], bE[n1][kk2], acc2[mt2][n1], 0, 0, 0);
        }

        // ---- diag: dump unnormalized e to att_maps (normalized by kernel 2) ----
        if (diag) {
            const int t = tid >> 2, ssg = (tid & 3) << 4;
            float* ap = attb + (long)t * S + s0 + ssg;
#pragma unroll
            for (int j = 0; j < 16; ++j) ap[j] = bf2f(ET[t * 72 + ssg + j]);
        }
        __syncthreads();
    }

    // ---- diag: reduce denominators denom[t] = sum_s e ----
    if (diag) {
        float d[16];
#pragma unroll
        for (int k = 0; k < 16; ++k) d[k] = dnacc[k];
#pragma unroll
        for (int k = 0; k < 16; ++k) {
            d[k] += __shfl_xor(d[k], 1); d[k] += __shfl_xor(d[k], 2);
            d[k] += __shfl_xor(d[k], 4); d[k] += __shfl_xor(d[k], 8);
        }
        if (cl == 0) {
#pragma unroll
            for (int mt = 0; mt < 4; ++mt)
#pragma unroll
                for (int r = 0; r < 4; ++r)
                    red[(w << 6) + mt * 16 + (q << 2) + r] = d[mt * 4 + r];
        }
        __syncthreads();
        if (tid < 64)
            ws[256 + b * 64 + tid] = red[tid] + red[64 + tid] + red[128 + tid] + red[192 + tid];
        __syncthreads();
    }

    // ---- cosine + row log-sum-exp (denominator cancels in cos) ----
    {
        float pn[4] = {0.f, 0.f, 0.f, 0.f}, pw[4] = {0.f, 0.f, 0.f, 0.f};
#pragma unroll
        for (int mt2 = 0; mt2 < 2; ++mt2)
#pragma unroll
            for (int r = 0; r < 4; ++r) {
                const int e_idx = (w << 5) + (mt2 << 4) + (q << 2) + r;
#pragma unroll
                for (int n1 = 0; n1 < 4; ++n1) {
                    const float wcv = acc2[mt2][n1][r];
                    const float tv  = txt[((long)i * T + (n1 << 4) + cl) * E + e_idx] * tinv[n1];
                    pn[n1] = fmaf(wcv, tv, pn[n1]);
                    pw[n1] = fmaf(wcv, wcv, pw[n1]);
                }
            }
#pragma unroll
        for (int n1 = 0; n1 < 4; ++n1) {
            pn[n1] += __shfl_xor(pn[n1], 16); pn[n1] += __shfl_xor(pn[n1], 32);
            pw[n1] += __shfl_xor(pw[n1], 16); pw[n1] += __shfl_xor(pw[n1], 32);
        }
        if (q == 0) {
#pragma unroll
            for (int n1 = 0; n1 < 4; ++n1) {
                red [(w << 6) + (n1 << 4) + cl] = pn[n1];
                red2[(w << 6) + (n1 << 4) + cl] = pw[n1];
            }
        }
        __syncthreads();
        if (tid < 64) {
            const float num = red [tid] + red [64 + tid] + red [128 + tid] + red [192 + tid];
            const float w2s = red2[tid] + red2[64 + tid] + red2[128 + tid] + red2[192 + tid];
            const float cosv = num / fmaxf(sqrtf(w2s), 1e-8f);   // ||tn||=1; denom cancels
            float r = __expf(5.0f * cosv);
#pragma unroll
            for (int m = 1; m < 64; m <<= 1) r += __shfl_xor(r, m);
            if (tid == 0) ws[b * 16 + i] = 10.0f * logf(r);
        }
    }
}

// att_maps[b][t][:] *= 1/denom[b][t]. Region starts at d_out+1 (4B misaligned).
__global__ __launch_bounds__(256, 4)
void att_norm_kernel(float* __restrict__ d_out, const float* __restrict__ ws)
{
    const int bt = blockIdx.x;
    const float inv = 1.0f / ws[256 + bt];
    float* p = d_out + 1 + (long)bt * 4096;
#pragma unroll
    for (int k = 0; k < 16; ++k)
        p[k * 256 + threadIdx.x] *= inv;
}

// Final 16x16 symmetric cross-entropy.
__global__ __launch_bounds__(256, 1)
void loss_kernel(const float* __restrict__ ws, float* __restrict__ d_out)
{
    __shared__ float sm[16][17];
    __shared__ float red[16];
    const int tid = threadIdx.x;
    const int bb = tid >> 4, ii = tid & 15;
    const float x = ws[bb * 16 + ii];
    sm[bb][ii] = x;

    float m = x;
#pragma unroll
    for (int msk = 1; msk < 16; msk <<= 1) m = fmaxf(m, __shfl_xor(m, msk));
    float s = __expf(x - m);
#pragma unroll
    for (int msk = 1; msk < 16; msk <<= 1) s += __shfl_xor(s, msk);
    const float lsm0 = x - m - logf(s);

    __syncthreads();
    const float y = sm[ii][bb];
    float m1 = y;
#pragma unroll
    for (int msk = 1; msk < 16; msk <<= 1) m1 = fmaxf(m1, __shfl_xor(m1, msk));
    float s1 = __expf(y - m1);
#pragma unroll
    for (int msk = 1; msk < 16; msk <<= 1) s1 += __shfl_xor(s1, msk);
    const float lsm1 = y - m1 - logf(s1);

    if (bb == ii) red[bb] = lsm0 + lsm1;
    __syncthreads();
    if (tid == 0) {
        float tot = 0.f;
#pragma unroll
        for (int k = 0; k < 16; ++k) tot += red[k];
        d_out[0] = -tot / 32.0f;
    }
}

extern "C" void kernel_launch(void* const* d_in, const int* in_sizes, int n_in,
                              void* d_out, int out_size, void* d_ws, size_t ws_size,
                              hipStream_t stream)
{
    const float* vis = (const float*)d_in[0];
    const float* txt = (const float*)d_in[1];
    float* out = (float*)d_out;
    float* ws  = (float*)d_ws;   // [0..255] sims, [256..1279] diag denoms

    hipLaunchKernelGGL(clip_main_kernel, dim3(BS * BS), dim3(256), 0, stream,
                       vis, txt, out, ws);
    hipLaunchKernelGGL(att_norm_kernel, dim3(BS * T), dim3(256), 0, stream,
                       out, ws);
    hipLaunchKernelGGL(loss_kernel, dim3(1), dim3(256), 0, stream, ws, out);
}